// Round 1
// baseline (203.182 us; speedup 1.0000x reference)
//
#include <hip/hip_runtime.h>

// Policy MLP: B=131072 rows, 40 x (Linear(32,32)+ReLU) + Linear(32,1).
// fp32 throughout (CDNA4 has no fp32 MFMA -> pure VALU kernel).
// Strategy: 1 thread = 1 batch row; activations x[32] in VGPRs; weights are
// wave-uniform -> compiler emits s_load into SGPRs -> inner loop is
// v_fmac_f32 v, s, v (1024 FMAs/layer/thread, 32 independent chains).

#define NB 131072
#define D 32
#define L 40

__global__ __launch_bounds__(256) void policy_mlp_kernel(
    const float* __restrict__ state,
    const float* __restrict__ Wh,    // [L][D][D], row-major, W[l][o][i]
    const float* __restrict__ bh,    // [L][D]
    const float* __restrict__ Wout,  // [D]
    const float* __restrict__ bout,  // [1]
    float* __restrict__ out)         // [NB]
{
    const int row = blockIdx.x * blockDim.x + threadIdx.x;

    // Load this row's 32 activations as 8x float4 (128 B/thread).
    float x[D];
    const float4* sp = reinterpret_cast<const float4*>(state + (size_t)row * D);
    #pragma unroll
    for (int j = 0; j < D / 4; ++j) {
        float4 v = sp[j];
        x[4 * j + 0] = v.x;
        x[4 * j + 1] = v.y;
        x[4 * j + 2] = v.z;
        x[4 * j + 3] = v.w;
    }

    // 40 hidden layers. Keep the layer loop rolled; fully unroll the 32x32.
    #pragma unroll 1
    for (int l = 0; l < L; ++l) {
        const float* __restrict__ Wl = Wh + l * (D * D);
        const float* __restrict__ bl = bh + l * D;
        float y[D];
        #pragma unroll
        for (int o = 0; o < D; ++o) {
            float acc = bl[o];               // uniform -> SGPR
            #pragma unroll
            for (int i = 0; i < D; ++i) {
                acc = fmaf(x[i], Wl[o * D + i], acc);  // W uniform -> SGPR operand
            }
            y[o] = fmaxf(acc, 0.0f);         // ReLU
        }
        #pragma unroll
        for (int o = 0; o < D; ++o) x[o] = y[o];
    }

    // Final Linear(32, 1), no activation.
    float acc = bout[0];
    #pragma unroll
    for (int i = 0; i < D; ++i) acc = fmaf(x[i], Wout[i], acc);
    out[row] = acc;
}

extern "C" void kernel_launch(void* const* d_in, const int* in_sizes, int n_in,
                              void* d_out, int out_size, void* d_ws, size_t ws_size,
                              hipStream_t stream) {
    const float* state = (const float*)d_in[0];
    const float* Wh    = (const float*)d_in[1];
    const float* bh    = (const float*)d_in[2];
    const float* Wout  = (const float*)d_in[3];
    const float* bout  = (const float*)d_in[4];
    float* out = (float*)d_out;

    dim3 block(256);
    dim3 grid(NB / 256);  // 512 blocks, 131072 threads, 1 row/thread
    policy_mlp_kernel<<<grid, block, 0, stream>>>(state, Wh, bh, Wout, bout, out);
}

// Round 2
// 59.647 us; speedup vs baseline: 3.4064x; 3.4064x over previous
//
#include <hip/hip_runtime.h>

// Policy MLP via split-precision bf16 MFMA.
// B=131072, D=32, L=40 hidden + final 32->1 (treated as pseudo-layer 41).
//
// Per wave: 32 batch rows. D = W * X^T per layer with mfma_f32_32x32x16_bf16:
//   A = W [out x in] (fragment-swizzled tables in d_ws, hi+lo bf16 split)
//   B = X^T [in x batch] (batch index lives in lane&31 for BOTH D and B ->
//       layer chaining needs only permlane32_swap half-exchanges, no transpose)
//   bias folded in as a 9th MFMA: A cols {0,1} = bias_hi/lo, B = ones rows.
// x split: x = xhi + xlo (both bf16); 4 product terms => error ~2^-18/layer.

#define NB 131072
#define DD 32
#define NL 40
#define WTAB_BYTES ((NL + 1) * 4 * 64 * 16)  // 167936: int4 frags [41][4 grp][64 lane]
#define TAB_BYTES (WTAB_BYTES + (NL + 1) * 64 * 4)

typedef short bf16x8 __attribute__((ext_vector_type(8)));
typedef float f32x16 __attribute__((ext_vector_type(16)));

union Frag { int4 q; int i[4]; bf16x8 v; };

__device__ inline unsigned f2bf(float f) {  // fp32 -> bf16 bits, RNE
  unsigned u = __float_as_uint(f);
  return (u + 0x7fffu + ((u >> 16) & 1u)) >> 16;
}
__device__ inline float bf2f(unsigned s) { return __int_as_float((int)(s << 16)); }

// ---- table build: swizzle W/bias into MFMA A-fragment order --------------
// A-layout (32x32x16 bf16): lane l holds m=l&31, k = 8*(l>>5)+j, j=0..7,
// packed k-pairs per dword (even k in low 16). Frag group g: {hi,lo} x {kk=0,1}.
__global__ __launch_bounds__(64) void build_tables(
    const float* __restrict__ Wh, const float* __restrict__ bh,
    const float* __restrict__ Wout, const float* __restrict__ bout,
    int4* __restrict__ wtab, int* __restrict__ btab) {
  const int l = blockIdx.x;      // 0..40 (40 == output layer)
  const int lane = threadIdx.x;  // 0..63
  const int m = lane & 31, h = lane >> 5;
  for (int g = 0; g < 4; ++g) {
    const int kk = g & 1;
    const bool lopart = (g >= 2);
    int wds[4];
    for (int w = 0; w < 4; ++w) {
      const int k = 16 * kk + 8 * h + 2 * w;
      float a, b;
      if (l < NL) {
        a = Wh[(l * 32 + m) * 32 + k];
        b = Wh[(l * 32 + m) * 32 + k + 1];
      } else {  // final layer: row 0 = W_out, rest zero
        a = (m == 0) ? Wout[k] : 0.f;
        b = (m == 0) ? Wout[k + 1] : 0.f;
      }
      unsigned ah = f2bf(a), bhh = f2bf(b);
      unsigned al = f2bf(a - bf2f(ah)), bl = f2bf(b - bf2f(bhh));
      wds[w] = lopart ? (int)(al | (bl << 16)) : (int)(ah | (bhh << 16));
    }
    wtab[(l * 4 + g) * 64 + lane] = make_int4(wds[0], wds[1], wds[2], wds[3]);
  }
  float bv = (l < NL) ? bh[l * 32 + m] : ((m == 0) ? bout[0] : 0.f);
  unsigned bhi = f2bf(bv);
  unsigned blo = f2bf(bv - bf2f(bhi));
  btab[l * 64 + lane] = (h == 0) ? (int)(bhi | (blo << 16)) : 0;
}

// ---- main kernel ----------------------------------------------------------
__device__ inline int cvt_pk(float a, float b) {
  int r;
  asm("v_cvt_pk_bf16_f32 %0, %1, %2" : "=v"(r) : "v"(a), "v"(b));
  return r;
}
__device__ inline void pswap(int& a, int& b) {
  // a.hi_lanes <-> b.lo_lanes:  a' = [a_lo | b_lo-from-low-lanes], b' = [a_hi | b_hi]
  asm("v_permlane32_swap_b32 %0, %1" : "+v"(a), "+v"(b));
}
__device__ inline void split2(float a, float b, int& hi, int& lo) {
  hi = cvt_pk(a, b);
  float ha = __int_as_float(hi << 16);
  float hb = __int_as_float(hi & (int)0xffff0000u);
  lo = cvt_pk(a - ha, b - hb);  // exact residuals, then RNE to bf16
}

__global__ __launch_bounds__(256) void policy_mfma(
    const float* __restrict__ state, const int4* __restrict__ wtab,
    const int* __restrict__ btab, float* __restrict__ out) {
  const int lane = threadIdx.x & 63;
  const int wid = (int)((blockIdx.x * blockDim.x + threadIdx.x) >> 6);
  const int n = lane & 31, h = lane >> 5;
  const int bbase = wid * 32;

  // Layer-0 B-operand (X^T) frags straight from global state.
  // B-layout: lane holds col n=lane&31, k = 8h+j (kk selects +16).
  Frag bhi0, bhi1, blo0, blo1;
  {
    const float* xr = state + (size_t)(bbase + n) * DD + 8 * h;
    float4 xa = *(const float4*)(xr);       // k = 8h+0..3   (kk=0)
    float4 xb = *(const float4*)(xr + 4);   // k = 8h+4..7
    float4 xc = *(const float4*)(xr + 16);  // k = 16+8h+0..3 (kk=1)
    float4 xd = *(const float4*)(xr + 20);
    split2(xa.x, xa.y, bhi0.i[0], blo0.i[0]);
    split2(xa.z, xa.w, bhi0.i[1], blo0.i[1]);
    split2(xb.x, xb.y, bhi0.i[2], blo0.i[2]);
    split2(xb.z, xb.w, bhi0.i[3], blo0.i[3]);
    split2(xc.x, xc.y, bhi1.i[0], blo1.i[0]);
    split2(xc.z, xc.w, bhi1.i[1], blo1.i[1]);
    split2(xd.x, xd.y, bhi1.i[2], blo1.i[2]);
    split2(xd.z, xd.w, bhi1.i[3], blo1.i[3]);
  }

  Frag bones;  // B for the bias MFMA: rows k=0,1 all-ones
  bones.i[0] = (h == 0) ? 0x3F803F80 : 0;
  bones.i[1] = bones.i[2] = bones.i[3] = 0;

  const f32x16 zero16 = {0, 0, 0, 0, 0, 0, 0, 0, 0, 0, 0, 0, 0, 0, 0, 0};

  // prefetch layer 0 fragments
  int4 nw0 = wtab[lane], nw1 = wtab[64 + lane], nw2 = wtab[128 + lane],
       nw3 = wtab[192 + lane];
  int nb = btab[lane];

  float result = 0.f;

#pragma unroll 1
  for (int l = 0; l <= NL; ++l) {
    Frag wh0, wh1, wl0, wl1, ab;
    wh0.q = nw0; wh1.q = nw1; wl0.q = nw2; wl1.q = nw3;
    ab.i[0] = nb; ab.i[1] = ab.i[2] = ab.i[3] = 0;
    if (l < NL) {  // prefetch next layer
      const int base = (l + 1) * 4 * 64 + lane;
      nw0 = wtab[base];
      nw1 = wtab[base + 64];
      nw2 = wtab[base + 128];
      nw3 = wtab[base + 192];
      nb = btab[(l + 1) * 64 + lane];
    }

    f32x16 acc = __builtin_amdgcn_mfma_f32_32x32x16_bf16(ab.v, bones.v, zero16, 0, 0, 0);
    acc = __builtin_amdgcn_mfma_f32_32x32x16_bf16(wh0.v, bhi0.v, acc, 0, 0, 0);
    acc = __builtin_amdgcn_mfma_f32_32x32x16_bf16(wh1.v, bhi1.v, acc, 0, 0, 0);
    acc = __builtin_amdgcn_mfma_f32_32x32x16_bf16(wl0.v, bhi0.v, acc, 0, 0, 0);
    acc = __builtin_amdgcn_mfma_f32_32x32x16_bf16(wl1.v, bhi1.v, acc, 0, 0, 0);
    acc = __builtin_amdgcn_mfma_f32_32x32x16_bf16(wh0.v, blo0.v, acc, 0, 0, 0);
    acc = __builtin_amdgcn_mfma_f32_32x32x16_bf16(wh1.v, blo1.v, acc, 0, 0, 0);
    acc = __builtin_amdgcn_mfma_f32_32x32x16_bf16(wl0.v, blo0.v, acc, 0, 0, 0);
    acc = __builtin_amdgcn_mfma_f32_32x32x16_bf16(wl1.v, blo1.v, acc, 0, 0, 0);

    if (l < NL) {
      // relu + hi/lo split + half-swap -> next layer's B frags.
      // D row of reg r: o = (r&3) + 8*(r>>2) + 4h; pack reg pairs (2p,2p+1).
      int Hh[8], Hl[8];
#pragma unroll
      for (int p = 0; p < 8; ++p) {
        float a = fmaxf(acc[2 * p], 0.f);
        float b = fmaxf(acc[2 * p + 1], 0.f);
        split2(a, b, Hh[p], Hl[p]);
      }
      pswap(Hh[0], Hh[2]); pswap(Hh[1], Hh[3]);
      pswap(Hh[4], Hh[6]); pswap(Hh[5], Hh[7]);
      pswap(Hl[0], Hl[2]); pswap(Hl[1], Hl[3]);
      pswap(Hl[4], Hl[6]); pswap(Hl[5], Hl[7]);
      bhi0.i[0] = Hh[0]; bhi0.i[1] = Hh[1]; bhi0.i[2] = Hh[2]; bhi0.i[3] = Hh[3];
      bhi1.i[0] = Hh[4]; bhi1.i[1] = Hh[5]; bhi1.i[2] = Hh[6]; bhi1.i[3] = Hh[7];
      blo0.i[0] = Hl[0]; blo0.i[1] = Hl[1]; blo0.i[2] = Hl[2]; blo0.i[3] = Hl[3];
      blo1.i[0] = Hl[4]; blo1.i[1] = Hl[5]; blo1.i[2] = Hl[6]; blo1.i[3] = Hl[7];
    } else {
      result = acc[0];  // D[0][n] = out for batch col n (h==0 lanes)
    }
  }

  if (h == 0) out[bbase + n] = result;
}

extern "C" void kernel_launch(void* const* d_in, const int* in_sizes, int n_in,
                              void* d_out, int out_size, void* d_ws, size_t ws_size,
                              hipStream_t stream) {
  const float* state = (const float*)d_in[0];
  const float* Wh    = (const float*)d_in[1];
  const float* bh    = (const float*)d_in[2];
  const float* Wout  = (const float*)d_in[3];
  const float* bout  = (const float*)d_in[4];
  float* out = (float*)d_out;

  int4* wtab = (int4*)d_ws;
  int* btab  = (int*)((char*)d_ws + WTAB_BYTES);

  build_tables<<<NL + 1, 64, 0, stream>>>(Wh, bh, Wout, bout, wtab, btab);

  // 131072 rows / 32 per wave = 4096 waves; 256-thread blocks -> 1024 blocks.
  policy_mfma<<<(NB / 32) * 64 / 256, 256, 0, stream>>>(state, wtab, btab, out);
}

// Round 3
// 52.117 us; speedup vs baseline: 3.8986x; 1.1445x over previous
//
#include <hip/hip_runtime.h>

// Policy MLP via split-precision bf16 MFMA (round 3).
// B=131072, D=32, L=40 hidden + final 32->1 (pseudo-layer 41).
//
// Per wave: 32 batch rows. D = W * X^T per layer with mfma_f32_32x32x16_bf16.
// Key trick this round: the contraction pairs A and B by POSITION (h,j), so we
// store the k-axis permuted by
//     pi(kk,h,w,e) = 16*kk + 8*(w>>1) + 4*h + 2*(w&1) + e
// in BOTH the weight tables (A) and activations (B). With this ordering, the
// D-output's natural register layout (row o=(r&3)+8(r>>2)+4h, packed in reg
// pairs) IS the next layer's B layout -> no permlane32_swap at all.
// Terms kept: W_hi*x_hi + W_hi*x_lo + W_lo*x_hi (+bias MFMA). lo*lo dropped
// (~2^-18 rel/layer).

#define NB 131072
#define DD 32
#define NL 40
#define WTAB_BYTES ((NL + 1) * 4 * 64 * 16)

typedef short bf16x8 __attribute__((ext_vector_type(8)));
typedef float f32x16 __attribute__((ext_vector_type(16)));

union Frag { int4 q; int i[4]; bf16x8 v; };

__device__ inline unsigned f2bf(float f) {  // fp32 -> bf16 bits, RNE
  unsigned u = __float_as_uint(f);
  return (u + 0x7fffu + ((u >> 16) & 1u)) >> 16;
}
__device__ inline float bf2f(unsigned s) { return __int_as_float((int)(s << 16)); }

// ---- table build: W/bias into pi-permuted MFMA A-fragment order ----------
__global__ __launch_bounds__(64) void build_tables(
    const float* __restrict__ Wh, const float* __restrict__ bh,
    const float* __restrict__ Wout, const float* __restrict__ bout,
    int4* __restrict__ wtab, int* __restrict__ btab) {
  const int l = blockIdx.x;      // 0..40 (40 == output layer)
  const int lane = threadIdx.x;  // 0..63
  const int m = lane & 31, h = lane >> 5;
  for (int g = 0; g < 4; ++g) {        // {hi,lo} x {kk}
    const int kk = g & 1;
    const bool lopart = (g >= 2);
    int wds[4];
    for (int w = 0; w < 4; ++w) {
      const int k = 16 * kk + 8 * (w >> 1) + 4 * h + 2 * (w & 1);  // pi(...)
      float a, b;
      if (l < NL) {
        a = Wh[(l * 32 + m) * 32 + k];
        b = Wh[(l * 32 + m) * 32 + k + 1];
      } else {  // final layer: row 0 = W_out, rest zero
        a = (m == 0) ? Wout[k] : 0.f;
        b = (m == 0) ? Wout[k + 1] : 0.f;
      }
      unsigned ah = f2bf(a), bhh = f2bf(b);
      unsigned al = f2bf(a - bf2f(ah)), bl = f2bf(b - bf2f(bhh));
      wds[w] = lopart ? (int)(al | (bl << 16)) : (int)(ah | (bhh << 16));
    }
    wtab[(l * 4 + g) * 64 + lane] = make_int4(wds[0], wds[1], wds[2], wds[3]);
  }
  // bias MFMA A-operand: bias_hi at position j=0, bias_lo at j=1 (h'==0 only)
  float bv = (l < NL) ? bh[l * 32 + m] : ((m == 0) ? bout[0] : 0.f);
  unsigned bhi = f2bf(bv);
  unsigned blo = f2bf(bv - bf2f(bhi));
  btab[l * 64 + lane] = (h == 0) ? (int)(bhi | (blo << 16)) : 0;
}

// ---- main kernel ----------------------------------------------------------
__device__ inline int cvt_pk(float a, float b) {  // a -> lo16, b -> hi16
  int r;
  asm("v_cvt_pk_bf16_f32 %0, %1, %2" : "=v"(r) : "v"(a), "v"(b));
  return r;
}
__device__ inline void split2(float a, float b, int& hi, int& lo) {
  hi = cvt_pk(a, b);
  float ha = __int_as_float(hi << 16);
  float hb = __int_as_float(hi & (int)0xffff0000u);
  lo = cvt_pk(a - ha, b - hb);
}

__global__ __launch_bounds__(256) void policy_mfma(
    const float* __restrict__ state, const int4* __restrict__ wtab,
    const int* __restrict__ btab, float* __restrict__ out) {
  const int lane = threadIdx.x & 63;
  const int wid = (int)((blockIdx.x * blockDim.x + threadIdx.x) >> 6);
  const int n = lane & 31, h = lane >> 5;
  const int bbase = wid * 32;

  // Layer-0 B-operand (X^T) frags, pi-permuted layout:
  // position (kk,h,w=0,1) <- x[16kk+4h+0..3], (w=2,3) <- x[16kk+8+4h+0..3]
  Frag bhi0, bhi1, blo0, blo1;
  {
    const float* xr = state + (size_t)(bbase + n) * DD;
    float4 xa = *(const float4*)(xr + 4 * h);
    float4 xb = *(const float4*)(xr + 8 + 4 * h);
    float4 xc = *(const float4*)(xr + 16 + 4 * h);
    float4 xd = *(const float4*)(xr + 24 + 4 * h);
    split2(xa.x, xa.y, bhi0.i[0], blo0.i[0]);
    split2(xa.z, xa.w, bhi0.i[1], blo0.i[1]);
    split2(xb.x, xb.y, bhi0.i[2], blo0.i[2]);
    split2(xb.z, xb.w, bhi0.i[3], blo0.i[3]);
    split2(xc.x, xc.y, bhi1.i[0], blo1.i[0]);
    split2(xc.z, xc.w, bhi1.i[1], blo1.i[1]);
    split2(xd.x, xd.y, bhi1.i[2], blo1.i[2]);
    split2(xd.z, xd.w, bhi1.i[3], blo1.i[3]);
  }

  Frag bones;  // B for the bias MFMA: positions (h=0, j=0,1) = 1.0
  bones.i[0] = (h == 0) ? 0x3F803F80 : 0;
  bones.i[1] = bones.i[2] = bones.i[3] = 0;

  Frag ab;  // bias A frag (dword 0 per-layer, rest zero)
  ab.i[1] = ab.i[2] = ab.i[3] = 0;

  const f32x16 zero16 = {0, 0, 0, 0, 0, 0, 0, 0, 0, 0, 0, 0, 0, 0, 0, 0};

  // prefetch layer 0 fragments (pointers advance by uniform stride -> SGPR adds)
  const int4* wp = wtab + lane;
  const int* bp = btab + lane;
  int4 nw0 = wp[0], nw1 = wp[64], nw2 = wp[128], nw3 = wp[192];
  int nb = bp[0];

  float result = 0.f;

#pragma unroll 1
  for (int l = 0; l <= NL; ++l) {
    Frag wh0, wh1, wl0, wl1;
    wh0.q = nw0; wh1.q = nw1; wl0.q = nw2; wl1.q = nw3;
    ab.i[0] = nb;
    if (l < NL) {  // prefetch next layer
      wp += 256; bp += 64;
      nw0 = wp[0]; nw1 = wp[64]; nw2 = wp[128]; nw3 = wp[192];
      nb = bp[0];
    }

    f32x16 acc = __builtin_amdgcn_mfma_f32_32x32x16_bf16(ab.v, bones.v, zero16, 0, 0, 0);
    acc = __builtin_amdgcn_mfma_f32_32x32x16_bf16(wh0.v, bhi0.v, acc, 0, 0, 0);
    acc = __builtin_amdgcn_mfma_f32_32x32x16_bf16(wl0.v, bhi0.v, acc, 0, 0, 0);
    acc = __builtin_amdgcn_mfma_f32_32x32x16_bf16(wh1.v, bhi1.v, acc, 0, 0, 0);
    acc = __builtin_amdgcn_mfma_f32_32x32x16_bf16(wl1.v, bhi1.v, acc, 0, 0, 0);
    acc = __builtin_amdgcn_mfma_f32_32x32x16_bf16(wh0.v, blo0.v, acc, 0, 0, 0);
    acc = __builtin_amdgcn_mfma_f32_32x32x16_bf16(wh1.v, blo1.v, acc, 0, 0, 0);

    if (l < NL) {
      // relu + hi/lo split; pi layout makes reg-pair p land directly at
      // B position (kk=p>>2, w=p&3) -> straight assignment, no lane swaps.
#pragma unroll
      for (int p = 0; p < 8; ++p) {
        float a = fmaxf(acc[2 * p], 0.f);
        float b = fmaxf(acc[2 * p + 1], 0.f);
        int hi, lo;
        split2(a, b, hi, lo);
        if (p < 4) { bhi0.i[p] = hi; blo0.i[p] = lo; }
        else       { bhi1.i[p - 4] = hi; blo1.i[p - 4] = lo; }
      }
    } else {
      result = acc[0];  // D row 0 (h==0 lanes), col n = batch
    }
  }

  if (h == 0) out[bbase + n] = result;
}

extern "C" void kernel_launch(void* const* d_in, const int* in_sizes, int n_in,
                              void* d_out, int out_size, void* d_ws, size_t ws_size,
                              hipStream_t stream) {
  const float* state = (const float*)d_in[0];
  const float* Wh    = (const float*)d_in[1];
  const float* bh    = (const float*)d_in[2];
  const float* Wout  = (const float*)d_in[3];
  const float* bout  = (const float*)d_in[4];
  float* out = (float*)d_out;

  int4* wtab = (int4*)d_ws;
  int* btab  = (int*)((char*)d_ws + WTAB_BYTES);

  build_tables<<<NL + 1, 64, 0, stream>>>(Wh, bh, Wout, bout, wtab, btab);

  // 131072 rows / 32 per wave = 4096 waves; 256-thread blocks -> 1024 blocks.
  policy_mfma<<<(NB / 32) * 64 / 256, 256, 0, stream>>>(state, wtab, btab, out);
}